// Round 6
// baseline (329.003 us; speedup 1.0000x reference)
//
#include <hip/hip_runtime.h>
#include <hip/hip_bf16.h>

// NestedAttention: B=16,N=1024,D=1024,E=4,H=16,hd=64
// bf16 MFMA pipeline with fp32 accumulate.
// R6: expert-sorted tokens -> nested-K QKV GEMM (avg 47% K-work) and
// masked-block-skip proj GEMM (~50% work). GEMM schedule = R5 2-phase.

typedef __bf16 bf16_t;
typedef __bf16 bf16x8 __attribute__((ext_vector_type(8)));
typedef __bf16 bf16x4 __attribute__((ext_vector_type(4)));
typedef float f32x4 __attribute__((ext_vector_type(4)));
typedef float f32x16 __attribute__((ext_vector_type(16)));
typedef int i32x4 __attribute__((ext_vector_type(4)));

typedef __attribute__((address_space(1))) void gvoid;
typedef __attribute__((address_space(3))) void lvoid;

#define MFMA16(a, b, c) __builtin_amdgcn_mfma_f32_16x16x32_bf16((a), (b), (c), 0, 0, 0)
#define MFMA32(a, b, c) __builtin_amdgcn_mfma_f32_32x32x16_bf16((a), (b), (c), 0, 0, 0)
#define GLOAD_LDS16(gsrc, ldst) \
  __builtin_amdgcn_global_load_lds((gvoid*)(gsrc), (lvoid*)(ldst), 16, 0, 0)

// softmax scale 1/sqrt(64) folded with log2(e) into Q at QKV epilogue
#define QSCALE 0.18033688f

__device__ __forceinline__ unsigned cvtpk(float lo, float hi) {
  unsigned r;
  asm("v_cvt_pk_bf16_f32 %0, %1, %2" : "=v"(r) : "v"(lo), "v"(hi));
  return r;
}
__device__ __forceinline__ void pl32swap(unsigned& x, unsigned& y) {
  asm("v_permlane32_swap_b32 %0, %1" : "+v"(x), "+v"(y));
}

// ------------------------------------------------------------- sorting ----
// counting sort of 16384 tokens into 4 expert buckets (ascending expert).
// s[0..3]=hist, s[4..7]=bases, s[8..11]=cursors. Wave-coalesced atomics.
// Intra-bucket order is atomic-race-dependent, but every output row depends
// only on its own token -> output bits identical across replays.
__global__ void zero_s(int* s) { if (threadIdx.x < 12) s[threadIdx.x] = 0; }

__global__ __launch_bounds__(256) void hist_experts(
    const int* __restrict__ em, int* __restrict__ s) {
  const int t = blockIdx.x * 256 + threadIdx.x;
  const int e = em[t];
  const int lane = threadIdx.x & 63;
#pragma unroll
  for (int x = 0; x < 4; ++x) {
    const unsigned long long mk = __ballot(e == x);
    if (mk && lane == (int)__ffsll((unsigned long long)mk) - 1)
      atomicAdd(&s[x], (int)__popcll(mk));
  }
}

__global__ void scan_s(int* s) {
  s[4] = 0; s[5] = s[0]; s[6] = s[0] + s[1]; s[7] = s[0] + s[1] + s[2];
}

__global__ __launch_bounds__(256) void scatter_experts(
    const int* __restrict__ em, int* __restrict__ s, int* __restrict__ perm) {
  const int t = blockIdx.x * 256 + threadIdx.x;
  const int e = em[t];
  const int lane = threadIdx.x & 63;
  const unsigned long long below = ((unsigned long long)1 << lane) - 1;
#pragma unroll
  for (int x = 0; x < 4; ++x) {
    const unsigned long long mk = __ballot(e == x);
    if (mk == 0) continue;
    const int leader = (int)__ffsll((unsigned long long)mk) - 1;
    int b = 0;
    if (lane == leader) b = atomicAdd(&s[8 + x], (int)__popcll(mk));
    b = __shfl(b, leader);
    if (e == x) perm[s[4 + x] + b + (int)__popcll(mk & below)] = t;
  }
}

// ---------------------------------------------------------------- prep ----
__global__ __launch_bounds__(256) void prep_tokens(
    const float* __restrict__ x, const int* __restrict__ em,
    bf16_t* __restrict__ xq) {
  const int row = blockIdx.x;                 // token index 0..16383
  const int dt = 128 << em[row];              // nested dim: 128<<e
  const int d = threadIdx.x * 4;
  float4 v = ((const float4*)(x + (size_t)row * 1024))[threadIdx.x];
  const bool keep = d < dt;                   // dt multiple of 128 -> uniform per 4
  bf16x4 o;
  o[0] = (bf16_t)(keep ? v.x : 0.f);
  o[1] = (bf16_t)(keep ? v.y : 0.f);
  o[2] = (bf16_t)(keep ? v.z : 0.f);
  o[3] = (bf16_t)(keep ? v.w : 0.f);
  *((bf16x4*)(xq + (size_t)row * 1024 + d)) = o;
}

__global__ __launch_bounds__(256) void conv_w(
    const float* __restrict__ s, bf16_t* __restrict__ dvec) {
  const int i = blockIdx.x * 256 + threadIdx.x;  // grid sized exactly, no guard
  float4 v = ((const float4*)s)[i];
  bf16x4 o;
  o[0] = (bf16_t)v.x; o[1] = (bf16_t)v.y; o[2] = (bf16_t)v.z; o[3] = (bf16_t)v.w;
  ((bf16x4*)dvec)[i] = o;
}

// ---------------------------------------------------------------- GEMM ----
// C[m,f] = sum_k A[m,k] * Bw[f,k]  ("B^T" GEMM) over PERMUTED rows:
// logical row r -> token perm[r] (tokens sorted ascending by expert).
// 256x256 tile, BK=64, 8 waves (2M x 4N). m230-style 2-phase K-loop.
// EPI 0 (QKV): K-loop runs only to the block's max nested dim
//   (rows sorted -> last row has max d_tok; zeros beyond a row's own d_tok
//   make straddling blocks exact). Epilogue scatters q(scaled)/k/vT bf16
//   to ORIGINAL token positions.
// EPI 1 (proj): full K; blocks with colbase >= dt_max are all-masked ->
//   vectorized zero-store and exit. Otherwise per-row output mask.
// Block mapping rowblk = bid%64 round-robins experts across XCDs (balance).
template <int EPI>
__global__ __launch_bounds__(512, 2) void gemm256(
    const bf16_t* __restrict__ A, const bf16_t* __restrict__ Bw, int K,
    const int* __restrict__ perm,
    bf16_t* __restrict__ qo, bf16_t* __restrict__ ko, bf16_t* __restrict__ vto,
    float* __restrict__ yout, const float* __restrict__ bias,
    const int* __restrict__ em) {
  __shared__ bf16_t lds[2][32768];  // per buf: A 32KB + B 32KB (chunk-swizzled)
  const int tid = threadIdx.x;
  const int lane = tid & 63, w = tid >> 6;
  const int wm = w >> 2, wn = w & 3;
  const int g = lane >> 4, c16 = lane & 15;

  const int bid = blockIdx.x;
  const int rowbase = (bid & 63) * 256;   // 64 row-blocks, expert-interleaved
  const int colbase = (bid >> 6) * 256;

  // block's max nested dim (rows ascending by expert -> last row is max)
  const int dtmax = 128 << em[perm[rowbase + 255]];

  if constexpr (EPI == 1) {
    if (colbase >= dtmax) {  // whole block masked -> write zeros, done
      const float4 z = make_float4(0.f, 0.f, 0.f, 0.f);
#pragma unroll
      for (int i = 0; i < 32; ++i) {
        const int idx = i * 512 + tid;
        const int r = idx >> 6, c4 = idx & 63;
        const int ro = perm[rowbase + r];
        ((float4*)(yout + (size_t)ro * 1024 + colbase))[c4] = z;
      }
      return;
    }
  }

  const int NT = (EPI == 0) ? (dtmax >> 6) : (K >> 6);  // nested K for QKV

  // staging: thread stages 8x16B chunks/K-tile; linear LDS dest, inverse-
  // swizzled global source (chunk col = (tid&7) ^ (row&7); rule #21).
  // A rows gathered through perm.
  const int trow = tid >> 3;
  const int scol = (((tid & 7) ^ (trow & 7)) << 3);
  const bf16_t* pA[4];
#pragma unroll
  for (int j = 0; j < 4; ++j)
    pA[j] = A + (size_t)perm[rowbase + trow + j * 64] * K + scol;
  const bf16_t* pB = Bw + (size_t)(colbase + trow) * K + scol;

#define STAGE(j, koff, dst)                                        \
  GLOAD_LDS16(((j) < 4 ? pA[j] : pB + (size_t)(((j) - 4) * 64) * K) + \
                  (koff),                                          \
              (dst) + ((j) * 512 + tid) * 8)

  // swizzled fragment read: row R, k-chunk (kk*4+g), elem = R*64 + swz*8
#define LDFRAG(base, R, kk)            \
  (*(const bf16x8*)((base) + (size_t)(R) * 64 + \
                    (((((kk) << 2) + g) ^ (c16 & 7)) << 3)))

  f32x4 acc[8][4] = {};

  // prologue: stage K-tile 0, drain, publish
#pragma unroll
  for (int j = 0; j < 8; ++j) STAGE(j, 0, (bf16_t*)lds[0]);
  asm volatile("s_waitcnt vmcnt(0)" ::: "memory");
  __builtin_amdgcn_s_barrier();

  for (int t = 0; t < NT; ++t) {
    const bf16_t* Lb = lds[t & 1];
    const bf16_t* LbB = Lb + 16384;
    const bool pf = (t + 1) < NT;

    // issue next-tile staging FIRST (lands during this tile's compute)
    if (pf) {
      bf16_t* Sd = (bf16_t*)lds[(t + 1) & 1];
      const int koff = (t + 1) << 6;
#pragma unroll
      for (int j = 0; j < 8; ++j) STAGE(j, koff, Sd);
    }

    // quadrant compute, no intra-tile barriers: compiler interleaves
    // ds_read (counted lgkmcnt) with MFMA.
    bf16x8 af[4][2], af2[4][2], b0[2][2], b1[2][2];
#pragma unroll
    for (int mi = 0; mi < 4; ++mi)
#pragma unroll
      for (int kk = 0; kk < 2; ++kk)
        af[mi][kk] = LDFRAG(Lb, wm * 128 + mi * 16 + c16, kk);
#pragma unroll
    for (int ni = 0; ni < 2; ++ni)
#pragma unroll
      for (int kk = 0; kk < 2; ++kk)
        b0[ni][kk] = LDFRAG(LbB, wn * 64 + ni * 16 + c16, kk);
#pragma unroll
    for (int mi = 0; mi < 4; ++mi)
#pragma unroll
      for (int ni = 0; ni < 2; ++ni)
#pragma unroll
        for (int kk = 0; kk < 2; ++kk)
          acc[mi][ni] = MFMA16(af[mi][kk], b0[ni][kk], acc[mi][ni]);

#pragma unroll
    for (int ni = 0; ni < 2; ++ni)
#pragma unroll
      for (int kk = 0; kk < 2; ++kk)
        b1[ni][kk] = LDFRAG(LbB, wn * 64 + (ni + 2) * 16 + c16, kk);
#pragma unroll
    for (int mi = 0; mi < 4; ++mi)
#pragma unroll
      for (int ni = 0; ni < 2; ++ni)
#pragma unroll
        for (int kk = 0; kk < 2; ++kk)
          acc[mi][ni + 2] = MFMA16(af[mi][kk], b1[ni][kk], acc[mi][ni + 2]);

#pragma unroll
    for (int mi = 0; mi < 4; ++mi)
#pragma unroll
      for (int kk = 0; kk < 2; ++kk)
        af2[mi][kk] = LDFRAG(Lb, wm * 128 + (mi + 4) * 16 + c16, kk);
#pragma unroll
    for (int mi = 0; mi < 4; ++mi)
#pragma unroll
      for (int ni = 0; ni < 2; ++ni)
#pragma unroll
        for (int kk = 0; kk < 2; ++kk)
          acc[mi + 4][ni] = MFMA16(af2[mi][kk], b0[ni][kk], acc[mi + 4][ni]);

#pragma unroll
    for (int mi = 0; mi < 4; ++mi)
#pragma unroll
      for (int ni = 0; ni < 2; ++ni)
#pragma unroll
        for (int kk = 0; kk < 2; ++kk)
          acc[mi + 4][ni + 2] = MFMA16(af2[mi][kk], b1[ni][kk], acc[mi + 4][ni + 2]);

    // next tile's loads had the whole compute phase (~2.5k cyc) to land
    if (pf) asm volatile("s_waitcnt vmcnt(0)" ::: "memory");
    __builtin_amdgcn_s_barrier();
  }

  // C/D layout: col = lane&15, row = (lane>>4)*4 + reg  [m89/m91 verified]
  if constexpr (EPI == 0) {
    const int s = colbase >> 10;  // 0=q,1=k,2=v (uniform per block: 256|1024)
#pragma unroll
    for (int mi = 0; mi < 8; ++mi)
#pragma unroll
      for (int j = 0; j < 4; ++j) {
        const int row = perm[rowbase + wm * 128 + mi * 16 + g * 4 + j];  // token
        const int bb = row >> 10, n = row & 1023;
#pragma unroll
        for (int ni = 0; ni < 4; ++ni) {
          const int col = colbase + wn * 64 + ni * 16 + c16;  // f
          const float v = acc[mi][ni][j];
          const int h = (col >> 6) & 15, e = col & 63;
          const size_t bh = (size_t)(bb * 16 + h);
          if (s == 0)
            qo[(bh * 1024 + n) * 64 + e] = (bf16_t)(v * QSCALE);
          else if (s == 1)
            ko[(bh * 1024 + n) * 64 + e] = (bf16_t)v;
          else
            vto[(bh * 64 + e) * 1024 + n] = (bf16_t)v;  // V transposed
        }
      }
  } else {
#pragma unroll
    for (int mi = 0; mi < 8; ++mi)
#pragma unroll
      for (int j = 0; j < 4; ++j) {
        const int row = perm[rowbase + wm * 128 + mi * 16 + g * 4 + j];
        const int dt = 128 << em[row];
#pragma unroll
        for (int ni = 0; ni < 4; ++ni) {
          const int col = colbase + wn * 64 + ni * 16 + c16;
          const float v = acc[mi][ni][j] + bias[col];
          yout[(size_t)row * 1024 + col] = (col < dt) ? v : 0.f;
        }
      }
  }
#undef STAGE
#undef LDFRAG
}

// ----------------------------------------------------------- attention ----
// 8 waves x 32 q-rows = 256 q rows / block. KVBLK=64 double-buffered in LDS
// (K row-major [64key][64d], V^T [64d][64key], both XOR-swizzled).
// Swapped QK^T: S = mfma32(Kfrag, Qfrag) -> lane holds P-row slice for
// q = lane&31 in registers; softmax fully in-register; P->bf16 via
// cvt_pk + permlane32_swap feeds PV's A operand directly.
__global__ __launch_bounds__(512, 2) void attn256(
    const bf16_t* __restrict__ Q, const bf16_t* __restrict__ Kb,
    const bf16_t* __restrict__ VT, bf16_t* __restrict__ X) {
  __shared__ bf16_t Klds[2][4096];
  __shared__ bf16_t Vlds[2][4096];
  const int tid = threadIdx.x;
  const int w = tid >> 6, lane = tid & 63;
  const int k32 = lane & 31, q5 = lane >> 5;
  const int bh = blockIdx.y;
  const int qbase = blockIdx.x * 256 + w * 32;

  const bf16_t* Qbh = Q + (size_t)bh * 65536;
  const bf16_t* Kbh = Kb + (size_t)bh * 65536;
  const bf16_t* Vbh = VT + (size_t)bh * 65536;

  const int trow = tid >> 3;
  const int tslot = (tid & 7) ^ (trow & 7);
  const bf16_t* kg = Kbh + (size_t)trow * 64 + tslot * 8;
  const bf16_t* vg = Vbh + (size_t)trow * 1024 + tslot * 8;

  bf16x8 qf[4];
#pragma unroll
  for (int kc = 0; kc < 4; ++kc)
    qf[kc] = *(const bf16x8*)(Qbh + (size_t)(qbase + k32) * 64 + kc * 16 + q5 * 8);
  asm volatile("" ::"v"(qf[0]), "v"(qf[1]), "v"(qf[2]), "v"(qf[3]));

  const int rbase = k32 * 128 + q5 * 16;
  const int rswz = (k32 & 7) << 4;

  f32x16 O0 = {}, O1 = {};
  float m = -3.0e38f, lsum = 0.f;

  GLOAD_LDS16(kg, (bf16_t*)Klds[0] + tid * 8);
  GLOAD_LDS16(vg, (bf16_t*)Vlds[0] + tid * 8);

  for (int step = 0; step < 16; ++step) {
    const int buf = step & 1;
    if (step < 15) {
      GLOAD_LDS16(kg + (step + 1) * 4096, (bf16_t*)Klds[buf ^ 1] + tid * 8);
      GLOAD_LDS16(vg + (step + 1) * 64, (bf16_t*)Vlds[buf ^ 1] + tid * 8);
      asm volatile("s_waitcnt vmcnt(2)" ::: "memory");
    } else {
      asm volatile("s_waitcnt vmcnt(0)" ::: "memory");
    }
    __builtin_amdgcn_s_barrier();

    const char* Kl = (const char*)Klds[buf];
    const char* Vl = (const char*)Vlds[buf];

    f32x16 S0 = {}, S1 = {};
#pragma unroll
    for (int kc = 0; kc < 4; ++kc) {
      const int off = (rbase + kc * 32) ^ rswz;
      bf16x8 kf0 = *(const bf16x8*)(Kl + off);
      bf16x8 kf1 = *(const bf16x8*)(Kl + off + 4096);
      S0 = MFMA32(kf0, qf[kc], S0);
      S1 = MFMA32(kf1, qf[kc], S1);
    }

    float pm = fmaxf(S0[0], S1[0]);
#pragma unroll
    for (int r = 1; r < 16; ++r) pm = fmaxf(pm, fmaxf(S0[r], S1[r]));
    pm = fmaxf(pm, __shfl_xor(pm, 32));
    if (__any(pm > m + 8.f)) {           // defer-max, THR=8 (log2 domain)
      const float mnew = fmaxf(m, pm);
      const float corr = __builtin_amdgcn_exp2f(m - mnew);
      m = mnew;
      lsum *= corr;
      const int ci = __builtin_bit_cast(int, corr);
#pragma unroll
      for (int r = 0; r < 16; ++r) {
        const int qsel = (r & 3) + 8 * (r >> 2) + 4 * q5;
        const float cr = __builtin_bit_cast(
            float, __builtin_amdgcn_ds_bpermute(qsel << 2, ci));
        O0[r] *= cr;
        O1[r] *= cr;
      }
    }
    float ps = 0.f;
#pragma unroll
    for (int r = 0; r < 16; ++r) {
      float p = __builtin_amdgcn_exp2f(S0[r] - m);
      ps += p; S0[r] = p;
      p = __builtin_amdgcn_exp2f(S1[r] - m);
      ps += p; S1[r] = p;
    }
    lsum += ps;

#define MAKE_PA(PV, B0, PA)                            \
  {                                                    \
    unsigned a_ = cvtpk(PV[B0 + 0], PV[B0 + 1]);       \
    unsigned b_ = cvtpk(PV[B0 + 2], PV[B0 + 3]);       \
    unsigned c_ = cvtpk(PV[B0 + 4], PV[B0 + 5]);       \
    unsigned d_ = cvtpk(PV[B0 + 6], PV[B0 + 7]);       \
    pl32swap(a_, c_);                                  \
    pl32swap(b_, d_);                                  \
    i32x4 wv_;                                         \
    wv_[0] = a_; wv_[1] = b_; wv_[2] = c_; wv_[3] = d_; \
    PA = __builtin_bit_cast(bf16x8, wv_);              \
  }
#define PV_STEP(PV, B0, KS)                                       \
  {                                                               \
    bf16x8 pa;                                                    \
    MAKE_PA(PV, B0, pa);                                          \
    const int voff = (rbase + (KS) * 32) ^ rswz;                  \
    bf16x8 vf0 = *(const bf16x8*)(Vl + voff);                     \
    bf16x8 vf1 = *(const bf16x8*)(Vl + voff + 4096);              \
    O0 = MFMA32(pa, vf0, O0);                                     \
    O1 = MFMA32(pa, vf1, O1);                                     \
  }
    PV_STEP(S0, 0, 0)
    PV_STEP(S0, 8, 1)
    PV_STEP(S1, 0, 2)
    PV_STEP(S1, 8, 3)

    __builtin_amdgcn_s_barrier();
  }

  lsum += __shfl_xor(lsum, 32);
  const float rinv = 1.f / lsum;
  const int ri = __builtin_bit_cast(int, rinv);
  const int bb = bh >> 4, h = bh & 15;
  bf16_t* Xb = X + (size_t)bb * 1024 * 1024 + h * 64;
#pragma unroll
  for (int r = 0; r < 16; ++r) {
    const int qsel = (r & 3) + 8 * (r >> 2) + 4 * q5;
    const float rv = __builtin_bit_cast(
        float, __builtin_amdgcn_ds_bpermute(qsel << 2, ri));
    const size_t rowoff = (size_t)(qbase + qsel) * 1024;
    Xb[rowoff + k32] = (bf16_t)(O0[r] * rv);
    Xb[rowoff + 32 + k32] = (bf16_t)(O1[r] * rv);
  }
}

// --------------------------------------------------------------- launch ----
extern "C" void kernel_launch(void* const* d_in, const int* in_sizes, int n_in,
                              void* d_out, int out_size, void* d_ws,
                              size_t ws_size, hipStream_t stream) {
  const float* x = (const float*)d_in[0];
  const int* em = (const int*)d_in[1];
  const float* qkvw = (const float*)d_in[2];
  const float* projw = (const float*)d_in[3];
  const float* projb = (const float*)d_in[4];
  float* out = (float*)d_out;

  char* ws = (char*)d_ws;
  size_t off = 0;
  bf16_t* xin = (bf16_t*)(ws + off); off += (size_t)16384 * 1024 * 2;  // reused as Xattn
  bf16_t* wq  = (bf16_t*)(ws + off); off += (size_t)3072 * 1024 * 2;
  bf16_t* wp  = (bf16_t*)(ws + off); off += (size_t)1024 * 1024 * 2;
  bf16_t* Qb  = (bf16_t*)(ws + off); off += (size_t)256 * 1024 * 64 * 2;
  bf16_t* Kb  = (bf16_t*)(ws + off); off += (size_t)256 * 1024 * 64 * 2;
  bf16_t* VTb = (bf16_t*)(ws + off); off += (size_t)256 * 64 * 1024 * 2;
  int* scr    = (int*)(ws + off); off += 64;            // hist/base/cursor
  int* perm   = (int*)(ws + off); off += 16384 * 4;     // token permutation

  // counting sort of tokens by expert
  zero_s<<<1, 16, 0, stream>>>(scr);
  hist_experts<<<64, 256, 0, stream>>>(em, scr);
  scan_s<<<1, 1, 0, stream>>>(scr);
  scatter_experts<<<64, 256, 0, stream>>>(em, scr, perm);

  prep_tokens<<<16384, 256, 0, stream>>>(x, em, xin);
  conv_w<<<3072, 256, 0, stream>>>(qkvw, wq);
  conv_w<<<1024, 256, 0, stream>>>(projw, wp);

  // QKV: M=16384 (permuted, nested-K), N=3072, K=1024 -> 64x12 blocks
  gemm256<0><<<768, 512, 0, stream>>>(
      xin, wq, 1024, perm, Qb, Kb, VTb, nullptr, nullptr, em);

  // attention: 4 q-tiles x 256 (b,h); writes Xattn into xin region
  attn256<<<dim3(4, 256), 512, 0, stream>>>(Qb, Kb, VTb, xin);

  // proj: M=16384 (permuted), N=1024, K=1024, masked-block skip -> 64x4
  gemm256<1><<<256, 512, 0, stream>>>(
      xin, wp, 1024, perm, nullptr, nullptr, nullptr, out, projb, em);
}

// Round 7
// 294.956 us; speedup vs baseline: 1.1154x; 1.1154x over previous
//
#include <hip/hip_runtime.h>
#include <hip/hip_bf16.h>

// NestedAttention: B=16,N=1024,D=1024,E=4,H=16,hd=64
// bf16 MFMA pipeline with fp32 accumulate.
// R7: PER-BATCH expert sort; whole pipeline runs in permuted token space
// (attention is permutation-equivariant within a batch). QKV gets nested-K
// (~58% work), proj gets masked-block skip (~60% work); no gather/scatter in
// GEMM hot paths -> no read/write amplification (R6's failure mode).

typedef __bf16 bf16_t;
typedef __bf16 bf16x8 __attribute__((ext_vector_type(8)));
typedef __bf16 bf16x4 __attribute__((ext_vector_type(4)));
typedef float f32x4 __attribute__((ext_vector_type(4)));
typedef float f32x16 __attribute__((ext_vector_type(16)));
typedef int i32x4 __attribute__((ext_vector_type(4)));

typedef __attribute__((address_space(1))) void gvoid;
typedef __attribute__((address_space(3))) void lvoid;

#define MFMA16(a, b, c) __builtin_amdgcn_mfma_f32_16x16x32_bf16((a), (b), (c), 0, 0, 0)
#define MFMA32(a, b, c) __builtin_amdgcn_mfma_f32_32x32x16_bf16((a), (b), (c), 0, 0, 0)
#define GLOAD_LDS16(gsrc, ldst) \
  __builtin_amdgcn_global_load_lds((gvoid*)(gsrc), (lvoid*)(ldst), 16, 0, 0)

// softmax scale 1/sqrt(64) folded with log2(e) into Q at QKV epilogue
#define QSCALE 0.18033688f

__device__ __forceinline__ unsigned cvtpk(float lo, float hi) {
  unsigned r;
  asm("v_cvt_pk_bf16_f32 %0, %1, %2" : "=v"(r) : "v"(lo), "v"(hi));
  return r;
}
__device__ __forceinline__ void pl32swap(unsigned& x, unsigned& y) {
  asm("v_permlane32_swap_b32 %0, %1" : "+v"(x), "+v"(y));
}

// ------------------------------------------------------------- sorting ----
// Per-batch counting sort (16 batches x 1024 tokens) into ascending-expert
// order. perm[b*1024+np] = original n; ems[b*1024+np] = expert. Bucket
// boundaries are deterministic (counts); within-bucket order is atomic-race
// dependent, but every output row depends only on its own token, so final
// outputs are bit-identical across replays.
__global__ __launch_bounds__(256) void sort_batch(
    const int* __restrict__ em, int* __restrict__ perm, int* __restrict__ ems) {
  __shared__ int cnt[4], base[4], cur[4];
  const int b = blockIdx.x, t = threadIdx.x;
  if (t < 4) cnt[t] = 0;
  __syncthreads();
  int e[4];
#pragma unroll
  for (int i = 0; i < 4; ++i) {
    e[i] = em[b * 1024 + t * 4 + i];
    atomicAdd(&cnt[e[i]], 1);
  }
  __syncthreads();
  if (t == 0) {
    base[0] = 0; base[1] = cnt[0];
    base[2] = cnt[0] + cnt[1]; base[3] = cnt[0] + cnt[1] + cnt[2];
    cur[0] = cur[1] = cur[2] = cur[3] = 0;
  }
  __syncthreads();
#pragma unroll
  for (int i = 0; i < 4; ++i) {
    const int pos = base[e[i]] + atomicAdd(&cur[e[i]], 1);
    perm[b * 1024 + pos] = t * 4 + i;
    ems[b * 1024 + pos] = e[i];
  }
}

// ---------------------------------------------------------------- prep ----
// gather token perm[np] of batch b -> permuted row np (coalesced 4KB row
// reads, contiguous writes), masked+converted to bf16.
__global__ __launch_bounds__(256) void prep_tokens(
    const float* __restrict__ x, const int* __restrict__ perm,
    const int* __restrict__ ems, bf16_t* __restrict__ xq) {
  const int prow = blockIdx.x;                // permuted row 0..16383
  const int orig = (prow & ~1023) + perm[prow];
  const int dt = 128 << ems[prow];            // token's nested dim
  const int d = threadIdx.x * 4;
  float4 v = ((const float4*)(x + (size_t)orig * 1024))[threadIdx.x];
  const bool keep = d < dt;                   // dt multiple of 128 -> uniform per 4
  bf16x4 o;
  o[0] = (bf16_t)(keep ? v.x : 0.f);
  o[1] = (bf16_t)(keep ? v.y : 0.f);
  o[2] = (bf16_t)(keep ? v.z : 0.f);
  o[3] = (bf16_t)(keep ? v.w : 0.f);
  *((bf16x4*)(xq + (size_t)prow * 1024 + d)) = o;
}

__global__ __launch_bounds__(256) void conv_w(
    const float* __restrict__ s, bf16_t* __restrict__ dvec) {
  const int i = blockIdx.x * 256 + threadIdx.x;  // grid sized exactly, no guard
  float4 v = ((const float4*)s)[i];
  bf16x4 o;
  o[0] = (bf16_t)v.x; o[1] = (bf16_t)v.y; o[2] = (bf16_t)v.z; o[3] = (bf16_t)v.w;
  ((bf16x4*)dvec)[i] = o;
}

// ---------------------------------------------------------------- GEMM ----
// C[m,f] = sum_k A[m,k] * Bw[f,k]  ("B^T" GEMM) over PERMUTED-space rows
// (contiguous; no gather). 256x256 tile, BK=64, 8 waves (2M x 4N),
// m230-style 2-phase K-loop, T2 chunk-swizzled LDS.
// EPI 0 (QKV): K-loop to the block's max nested dim (ascending experts ->
//   last row is max; zeros beyond a row's own dt keep straddle blocks
//   exact). Epilogue writes q(scaled)/k/vT at PERMUTED positions.
// EPI 1 (proj): full K; blocks with colbase >= dtmax write zeros (scattered
//   full 1KB rows) and exit; else per-row mask, scatter rows to orig pos.
template <int EPI>
__global__ __launch_bounds__(512, 2) void gemm256(
    const bf16_t* __restrict__ A, const bf16_t* __restrict__ Bw, int K,
    const int* __restrict__ perm, const int* __restrict__ ems,
    bf16_t* __restrict__ qo, bf16_t* __restrict__ ko, bf16_t* __restrict__ vto,
    float* __restrict__ yout, const float* __restrict__ bias) {
  __shared__ bf16_t lds[2][32768];  // per buf: A 32KB + B 32KB (chunk-swizzled)
  const int tid = threadIdx.x;
  const int lane = tid & 63, w = tid >> 6;
  const int wm = w >> 2, wn = w & 3;
  const int g = lane >> 4, c16 = lane & 15;

  const int bid = blockIdx.x;
  const int rowbase = (bid & 63) * 256;   // row-blocks cycle fastest (balance)
  const int colbase = (bid >> 6) * 256;

  // block's max nested dim (ascending experts within batch; 256 | 1024 so a
  // block never straddles batches)
  const int dtmax = 128 << ems[rowbase + 255];

  if constexpr (EPI == 1) {
    if (colbase >= dtmax) {  // whole block masked -> write zero rows, done
      const float4 z = make_float4(0.f, 0.f, 0.f, 0.f);
#pragma unroll
      for (int i = 0; i < 32; ++i) {
        const int idx = i * 512 + tid;
        const int r = idx >> 6, c4 = idx & 63;
        const int orow = ((rowbase + r) & ~1023) + perm[rowbase + r];
        ((float4*)(yout + (size_t)orow * 1024 + colbase))[c4] = z;
      }
      return;
    }
  }

  const int NT = (EPI == 0) ? (dtmax >> 6) : (K >> 6);  // nested K for QKV

  // staging: thread stages 8x16B chunks/K-tile; linear LDS dest, inverse-
  // swizzled global source (chunk col = (tid&7) ^ (row&7); rule #21).
  const int trow = tid >> 3;
  const int scol = (((tid & 7) ^ (trow & 7)) << 3);
  const bf16_t* pa = A + (size_t)(rowbase + trow) * K + scol;
  const bf16_t* pb = Bw + (size_t)(colbase + trow) * K + scol;

#define STAGE(j, koff, dst)                                       \
  GLOAD_LDS16(((j) < 4 ? pa + (size_t)((j) * 64) * K              \
                       : pb + (size_t)(((j) - 4) * 64) * K) +     \
                  (koff),                                         \
              (dst) + ((j) * 512 + tid) * 8)

  // swizzled fragment read: row R, k-chunk (kk*4+g), elem = R*64 + swz*8
#define LDFRAG(base, R, kk)            \
  (*(const bf16x8*)((base) + (size_t)(R) * 64 + \
                    (((((kk) << 2) + g) ^ (c16 & 7)) << 3)))

  f32x4 acc[8][4] = {};

  // prologue: stage K-tile 0, drain, publish
#pragma unroll
  for (int j = 0; j < 8; ++j) STAGE(j, 0, (bf16_t*)lds[0]);
  asm volatile("s_waitcnt vmcnt(0)" ::: "memory");
  __builtin_amdgcn_s_barrier();

  for (int t = 0; t < NT; ++t) {
    const bf16_t* Lb = lds[t & 1];
    const bf16_t* LbB = Lb + 16384;
    const bool pf = (t + 1) < NT;

    // issue next-tile staging FIRST (lands during this tile's compute)
    if (pf) {
      bf16_t* Sd = (bf16_t*)lds[(t + 1) & 1];
      const int koff = (t + 1) << 6;
#pragma unroll
      for (int j = 0; j < 8; ++j) STAGE(j, koff, Sd);
    }

    // quadrant compute, no intra-tile barriers: compiler interleaves
    // ds_read (counted lgkmcnt) with MFMA.
    bf16x8 af[4][2], af2[4][2], b0[2][2], b1[2][2];
#pragma unroll
    for (int mi = 0; mi < 4; ++mi)
#pragma unroll
      for (int kk = 0; kk < 2; ++kk)
        af[mi][kk] = LDFRAG(Lb, wm * 128 + mi * 16 + c16, kk);
#pragma unroll
    for (int ni = 0; ni < 2; ++ni)
#pragma unroll
      for (int kk = 0; kk < 2; ++kk)
        b0[ni][kk] = LDFRAG(LbB, wn * 64 + ni * 16 + c16, kk);
#pragma unroll
    for (int mi = 0; mi < 4; ++mi)
#pragma unroll
      for (int ni = 0; ni < 2; ++ni)
#pragma unroll
        for (int kk = 0; kk < 2; ++kk)
          acc[mi][ni] = MFMA16(af[mi][kk], b0[ni][kk], acc[mi][ni]);

#pragma unroll
    for (int ni = 0; ni < 2; ++ni)
#pragma unroll
      for (int kk = 0; kk < 2; ++kk)
        b1[ni][kk] = LDFRAG(LbB, wn * 64 + (ni + 2) * 16 + c16, kk);
#pragma unroll
    for (int mi = 0; mi < 4; ++mi)
#pragma unroll
      for (int ni = 0; ni < 2; ++ni)
#pragma unroll
        for (int kk = 0; kk < 2; ++kk)
          acc[mi][ni + 2] = MFMA16(af[mi][kk], b1[ni][kk], acc[mi][ni + 2]);

#pragma unroll
    for (int mi = 0; mi < 4; ++mi)
#pragma unroll
      for (int kk = 0; kk < 2; ++kk)
        af2[mi][kk] = LDFRAG(Lb, wm * 128 + (mi + 4) * 16 + c16, kk);
#pragma unroll
    for (int mi = 0; mi < 4; ++mi)
#pragma unroll
      for (int ni = 0; ni < 2; ++ni)
#pragma unroll
        for (int kk = 0; kk < 2; ++kk)
          acc[mi + 4][ni] = MFMA16(af2[mi][kk], b0[ni][kk], acc[mi + 4][ni]);

#pragma unroll
    for (int mi = 0; mi < 4; ++mi)
#pragma unroll
      for (int ni = 0; ni < 2; ++ni)
#pragma unroll
        for (int kk = 0; kk < 2; ++kk)
          acc[mi + 4][ni + 2] = MFMA16(af2[mi][kk], b1[ni][kk], acc[mi + 4][ni + 2]);

    // next tile's loads had the whole compute phase (~2.5k cyc) to land
    if (pf) asm volatile("s_waitcnt vmcnt(0)" ::: "memory");
    __builtin_amdgcn_s_barrier();
  }

  // C/D layout: col = lane&15, row = (lane>>4)*4 + reg  [m89/m91 verified]
  if constexpr (EPI == 0) {
    const int s = colbase >> 10;  // 0=q,1=k,2=v (uniform per block: 256|1024)
#pragma unroll
    for (int mi = 0; mi < 8; ++mi)
#pragma unroll
      for (int j = 0; j < 4; ++j) {
        const int row = rowbase + wm * 128 + mi * 16 + g * 4 + j;  // permuted
        const int bb = row >> 10, n = row & 1023;  // n = permuted position
#pragma unroll
        for (int ni = 0; ni < 4; ++ni) {
          const int col = colbase + wn * 64 + ni * 16 + c16;  // f
          const float v = acc[mi][ni][j];
          const int h = (col >> 6) & 15, e = col & 63;
          const size_t bh = (size_t)(bb * 16 + h);
          if (s == 0)
            qo[(bh * 1024 + n) * 64 + e] = (bf16_t)(v * QSCALE);
          else if (s == 1)
            ko[(bh * 1024 + n) * 64 + e] = (bf16_t)v;
          else
            vto[(bh * 64 + e) * 1024 + n] = (bf16_t)v;  // V transposed
        }
      }
  } else {
#pragma unroll
    for (int mi = 0; mi < 8; ++mi)
#pragma unroll
      for (int j = 0; j < 4; ++j) {
        const int row = rowbase + wm * 128 + mi * 16 + g * 4 + j;  // permuted
        const int dt = 128 << ems[row];
        const int orow = (row & ~1023) + perm[row];  // original token row
#pragma unroll
        for (int ni = 0; ni < 4; ++ni) {
          const int col = colbase + wn * 64 + ni * 16 + c16;
          const float v = acc[mi][ni][j] + bias[col];
          yout[(size_t)orow * 1024 + col] = (col < dt) ? v : 0.f;
        }
      }
  }
#undef STAGE
#undef LDFRAG
}

// ----------------------------------------------------------- attention ----
// Runs entirely in permuted token space (softmax over a batch's keys is
// permutation-invariant; each output row is its own query's result).
// 8 waves x 32 q-rows = 256 q rows / block. KVBLK=64 double-buffered in LDS
// (K row-major [64key][64d], V^T [64d][64key], both XOR-swizzled).
// Swapped QK^T: S = mfma32(Kfrag, Qfrag) -> lane holds P-row slice for
// q = lane&31 in registers; softmax fully in-register; P->bf16 via
// cvt_pk + permlane32_swap feeds PV's A operand directly.
__global__ __launch_bounds__(512, 2) void attn256(
    const bf16_t* __restrict__ Q, const bf16_t* __restrict__ Kb,
    const bf16_t* __restrict__ VT, bf16_t* __restrict__ X) {
  __shared__ bf16_t Klds[2][4096];
  __shared__ bf16_t Vlds[2][4096];
  const int tid = threadIdx.x;
  const int w = tid >> 6, lane = tid & 63;
  const int k32 = lane & 31, q5 = lane >> 5;
  const int bh = blockIdx.y;
  const int qbase = blockIdx.x * 256 + w * 32;

  const bf16_t* Qbh = Q + (size_t)bh * 65536;
  const bf16_t* Kbh = Kb + (size_t)bh * 65536;
  const bf16_t* Vbh = VT + (size_t)bh * 65536;

  const int trow = tid >> 3;
  const int tslot = (tid & 7) ^ (trow & 7);
  const bf16_t* kg = Kbh + (size_t)trow * 64 + tslot * 8;
  const bf16_t* vg = Vbh + (size_t)trow * 1024 + tslot * 8;

  bf16x8 qf[4];
#pragma unroll
  for (int kc = 0; kc < 4; ++kc)
    qf[kc] = *(const bf16x8*)(Qbh + (size_t)(qbase + k32) * 64 + kc * 16 + q5 * 8);
  asm volatile("" ::"v"(qf[0]), "v"(qf[1]), "v"(qf[2]), "v"(qf[3]));

  const int rbase = k32 * 128 + q5 * 16;
  const int rswz = (k32 & 7) << 4;

  f32x16 O0 = {}, O1 = {};
  float m = -3.0e38f, lsum = 0.f;

  GLOAD_LDS16(kg, (bf16_t*)Klds[0] + tid * 8);
  GLOAD_LDS16(vg, (bf16_t*)Vlds[0] + tid * 8);

  for (int step = 0; step < 16; ++step) {
    const int buf = step & 1;
    if (step < 15) {
      GLOAD_LDS16(kg + (step + 1) * 4096, (bf16_t*)Klds[buf ^ 1] + tid * 8);
      GLOAD_LDS16(vg + (step + 1) * 64, (bf16_t*)Vlds[buf ^ 1] + tid * 8);
      asm volatile("s_waitcnt vmcnt(2)" ::: "memory");
    } else {
      asm volatile("s_waitcnt vmcnt(0)" ::: "memory");
    }
    __builtin_amdgcn_s_barrier();

    const char* Kl = (const char*)Klds[buf];
    const char* Vl = (const char*)Vlds[buf];

    f32x16 S0 = {}, S1 = {};
#pragma unroll
    for (int kc = 0; kc < 4; ++kc) {
      const int off = (rbase + kc * 32) ^ rswz;
      bf16x8 kf0 = *(const bf16x8*)(Kl + off);
      bf16x8 kf1 = *(const bf16x8*)(Kl + off + 4096);
      S0 = MFMA32(kf0, qf[kc], S0);
      S1 = MFMA32(kf1, qf[kc], S1);
    }

    float pm = fmaxf(S0[0], S1[0]);
#pragma unroll
    for (int r = 1; r < 16; ++r) pm = fmaxf(pm, fmaxf(S0[r], S1[r]));
    pm = fmaxf(pm, __shfl_xor(pm, 32));
    if (__any(pm > m + 8.f)) {           // defer-max, THR=8 (log2 domain)
      const float mnew = fmaxf(m, pm);
      const float corr = __builtin_amdgcn_exp2f(m - mnew);
      m = mnew;
      lsum *= corr;
      const int ci = __builtin_bit_cast(int, corr);
#pragma unroll
      for (int r = 0; r < 16; ++r) {
        const int qsel = (r & 3) + 8 * (r >> 2) + 4 * q5;
        const float cr = __builtin_bit_cast(
            float, __builtin_amdgcn_ds_bpermute(qsel << 2, ci));
        O0[r] *= cr;
        O1[r] *= cr;
      }
    }
    float ps = 0.f;
#pragma unroll
    for (int r = 0; r < 16; ++r) {
      float p = __builtin_amdgcn_exp2f(S0[r] - m);
      ps += p; S0[r] = p;
      p = __builtin_amdgcn_exp2f(S1[r] - m);
      ps += p; S1[r] = p;
    }
    lsum += ps;

#define MAKE_PA(PV, B0, PA)                            \
  {                                                    \
    unsigned a_ = cvtpk(PV[B0 + 0], PV[B0 + 1]);       \
    unsigned b_ = cvtpk(PV[B0 + 2], PV[B0 + 3]);       \
    unsigned c_ = cvtpk(PV[B0 + 4], PV[B0 + 5]);       \
    unsigned d_ = cvtpk(PV[B0 + 6], PV[B0 + 7]);       \
    pl32swap(a_, c_);                                  \
    pl32swap(b_, d_);                                  \
    i32x4 wv_;                                         \
    wv_[0] = a_; wv_[1] = b_; wv_[2] = c_; wv_[3] = d_; \
    PA = __builtin_bit_cast(bf16x8, wv_);              \
  }
#define PV_STEP(PV, B0, KS)                                       \
  {                                                               \
    bf16x8 pa;                                                    \
    MAKE_PA(PV, B0, pa);                                          \
    const int voff = (rbase + (KS) * 32) ^ rswz;                  \
    bf16x8 vf0 = *(const bf16x8*)(Vl + voff);                     \
    bf16x8 vf1 = *(const bf16x8*)(Vl + voff + 4096);              \
    O0 = MFMA32(pa, vf0, O0);                                     \
    O1 = MFMA32(pa, vf1, O1);                                     \
  }
    PV_STEP(S0, 0, 0)
    PV_STEP(S0, 8, 1)
    PV_STEP(S1, 0, 2)
    PV_STEP(S1, 8, 3)

    __builtin_amdgcn_s_barrier();
  }

  lsum += __shfl_xor(lsum, 32);
  const float rinv = 1.f / lsum;
  const int ri = __builtin_bit_cast(int, rinv);
  const int bb = bh >> 4, h = bh & 15;
  bf16_t* Xb = X + (size_t)bb * 1024 * 1024 + h * 64;
#pragma unroll
  for (int r = 0; r < 16; ++r) {
    const int qsel = (r & 3) + 8 * (r >> 2) + 4 * q5;
    const float rv = __builtin_bit_cast(
        float, __builtin_amdgcn_ds_bpermute(qsel << 2, ri));
    const size_t rowoff = (size_t)(qbase + qsel) * 1024;
    Xb[rowoff + k32] = (bf16_t)(O0[r] * rv);
    Xb[rowoff + 32 + k32] = (bf16_t)(O1[r] * rv);
  }
}

// --------------------------------------------------------------- launch ----
extern "C" void kernel_launch(void* const* d_in, const int* in_sizes, int n_in,
                              void* d_out, int out_size, void* d_ws,
                              size_t ws_size, hipStream_t stream) {
  const float* x = (const float*)d_in[0];
  const int* em = (const int*)d_in[1];
  const float* qkvw = (const float*)d_in[2];
  const float* projw = (const float*)d_in[3];
  const float* projb = (const float*)d_in[4];
  float* out = (float*)d_out;

  char* ws = (char*)d_ws;
  size_t off = 0;
  bf16_t* xin = (bf16_t*)(ws + off); off += (size_t)16384 * 1024 * 2;  // reused as Xattn
  bf16_t* wq  = (bf16_t*)(ws + off); off += (size_t)3072 * 1024 * 2;
  bf16_t* wp  = (bf16_t*)(ws + off); off += (size_t)1024 * 1024 * 2;
  bf16_t* Qb  = (bf16_t*)(ws + off); off += (size_t)256 * 1024 * 64 * 2;
  bf16_t* Kb  = (bf16_t*)(ws + off); off += (size_t)256 * 1024 * 64 * 2;
  bf16_t* VTb = (bf16_t*)(ws + off); off += (size_t)256 * 64 * 1024 * 2;
  int* perm   = (int*)(ws + off); off += 16384 * 4;   // perm[b*1024+np] = n
  int* ems    = (int*)(ws + off); off += 16384 * 4;   // expert of sorted slot

  // per-batch counting sort (deterministic bucket structure)
  sort_batch<<<16, 256, 0, stream>>>(em, perm, ems);

  // gather tokens into permuted order + mask + bf16
  prep_tokens<<<16384, 256, 0, stream>>>(x, perm, ems, xin);
  conv_w<<<3072, 256, 0, stream>>>(qkvw, wq);
  conv_w<<<1024, 256, 0, stream>>>(projw, wp);

  // QKV: M=16384 (permuted space, nested-K), N=3072 -> 64x12 blocks
  gemm256<0><<<768, 512, 0, stream>>>(
      xin, wq, 1024, perm, ems, Qb, Kb, VTb, nullptr, nullptr);

  // attention in permuted space: 4 q-tiles x 256 (b,h); X -> xin region
  attn256<<<dim3(4, 256), 512, 0, stream>>>(Qb, Kb, VTb, xin);

  // proj: M=16384 (permuted), N=1024, masked-block skip, scatter epilogue
  gemm256<1><<<256, 512, 0, stream>>>(
      xin, wp, 1024, perm, ems, nullptr, nullptr, nullptr, out, projb);
}